// Round 1
// baseline (2001.449 us; speedup 1.0000x reference)
//
#include <hip/hip_runtime.h>

// TemporalCausalMaps on MI355X (gfx950).
// Design: per-sample independence => each block owns BS samples and walks the
// full (idx, node) nest locally; decoded state lives in LDS; no grid sync.
// All math fp32 (no fp32 MFMA on CDNA4; vector ALU is the right tool here).

#define BS 8
#define NTHREADS 256

__device__ __forceinline__ float sigm(float x) {
  return 1.0f / (1.0f + __expf(-x));
}
__device__ __forceinline__ float tanh_fast(float x) {
  x = fminf(15.0f, fmaxf(-15.0f, x));
  float e = __expf(2.0f * x);
  return (e - 1.0f) / (e + 1.0f);
}
__device__ __forceinline__ float leaky(float x) {
  return x >= 0.0f ? x : 0.01f * x;
}

__device__ __forceinline__ float dot24(const float* __restrict__ w, const float* h) {
  const float4* w4 = reinterpret_cast<const float4*>(w);
  const float4* h4 = reinterpret_cast<const float4*>(h);
  float acc = 0.0f;
#pragma unroll
  for (int i = 0; i < 6; ++i) {
    float4 a = w4[i]; float4 b = h4[i];
    acc = fmaf(a.x, b.x, acc); acc = fmaf(a.y, b.y, acc);
    acc = fmaf(a.z, b.z, acc); acc = fmaf(a.w, b.w, acc);
  }
  return acc;
}
__device__ __forceinline__ float dot48(const float* __restrict__ w, const float* h) {
  const float4* w4 = reinterpret_cast<const float4*>(w);
  const float4* h4 = reinterpret_cast<const float4*>(h);
  float acc = 0.0f;
#pragma unroll
  for (int i = 0; i < 12; ++i) {
    float4 a = w4[i]; float4 b = h4[i];
    acc = fmaf(a.x, b.x, acc); acc = fmaf(a.y, b.y, acc);
    acc = fmaf(a.z, b.z, acc); acc = fmaf(a.w, b.w, acc);
  }
  return acc;
}
__device__ __forceinline__ float dot64(const float* __restrict__ w, const float* h) {
  const float4* w4 = reinterpret_cast<const float4*>(w);
  const float4* h4 = reinterpret_cast<const float4*>(h);
  float acc = 0.0f;
#pragma unroll
  for (int i = 0; i < 16; ++i) {
    float4 a = w4[i]; float4 b = h4[i];
    acc = fmaf(a.x, b.x, acc); acc = fmaf(a.y, b.y, acc);
    acc = fmaf(a.z, b.z, acc); acc = fmaf(a.w, b.w, acc);
  }
  return acc;
}

// cond_net for node nn, output element e, scalar input xv:
// h = relu(xv * w1 + b1) (32); out_e = b2[e] + sum_k w2[e,k] * h[k]
__device__ __forceinline__ float cond_apply(
    const float* __restrict__ cw1, const float* __restrict__ cb1,
    const float* __restrict__ cw2, const float* __restrict__ cb2,
    int nn, int e, float xv) {
  const float* w1 = cw1 + nn * 32;
  const float* b1 = cb1 + nn * 32;
  const float* w2 = cw2 + (nn * 8 + e) * 32;
  float acc = cb2[nn * 8 + e];
#pragma unroll
  for (int k = 0; k < 32; ++k) {
    float hh = fmaf(xv, w1[k], b1[k]);
    hh = fmaxf(hh, 0.0f);
    acc = fmaf(w2[k], hh, acc);
  }
  return acc;
}

// LDS layout (floats), total 14208 = 56832 B:
//  [0,4096)      s_x (3072 used)  | s_d2 (4096)   -- disjoint lifetimes
//  [4096,5632)   s_h (1536)
//  [5632,7168)   s_g (1536)
//  [7168,11776)  s_gi (4608)      | s_d1 (4096)   -- disjoint lifetimes
//  [11776,13312) s_y (1536)
//  [13312,13696) s_hid (2 x 192, double buffer)
//  [13696,14208) s_dec (8 nodes x BS x 8 t)
__global__ __launch_bounds__(NTHREADS, 1) void tcm_kernel(
    const float* __restrict__ z,
    const float* __restrict__ cond_w1, const float* __restrict__ cond_b1,
    const float* __restrict__ cond_w2, const float* __restrict__ cond_b2,
    const float* __restrict__ proj_w, const float* __restrict__ proj_b,
    const float* __restrict__ gpw, const float* __restrict__ gpb,
    const float* __restrict__ gru_wih, const float* __restrict__ gru_whh,
    const float* __restrict__ gru_bih, const float* __restrict__ gru_bhh,
    const float* __restrict__ cm_w1, const float* __restrict__ cm_b1,
    const float* __restrict__ cm_w2, const float* __restrict__ cm_b2,
    const float* __restrict__ cm_w3, const float* __restrict__ cm_b3,
    const int* __restrict__ endw,
    float* __restrict__ out, int Btot) {
  __shared__ float lds[14208];
  float* s_x   = lds;            // stage-1 input [b][t][48]
  float* s_d2  = lds;            // causal-map hidden 2 [b][t][64]
  float* s_h   = lds + 4096;     // proj out [b][t][24]
  float* s_g   = lds + 5632;     // gru input [b][t][24]
  float* s_gi  = lds + 7168;     // input gates [b][t][72]
  float* s_d1  = lds + 7168;     // causal-map hidden 1 [b][t][64]
  float* s_y   = lds + 11776;    // GRU layer out [b][t][24]
  float* s_hid = lds + 13312;    // [2][BS][24] double-buffered hidden
  float* s_dec = lds + 13696;    // decoded [n][b][t]

  const int tid = threadIdx.x;
  const int gb0 = blockIdx.x * BS;
  const int T = endw[0];

#pragma unroll 1
  for (int idx = 0; idx < T; ++idx) {
    const int L = idx + 1;
#pragma unroll 1
    for (int n = 0; n < 8; ++n) {
      // ---- stage 1: assemble x[b][t][0:48]  (48 cols; node-0 tail zeroed)
#pragma unroll 1
      for (int it = tid; it < L * BS * 48; it += NTHREADS) {
        int t = it / (BS * 48);
        int b = (it / 48) & 7;
        int c = it % 48;
        float v = 0.0f;
        if (c < 32) {
          int gb = gb0 + b;
          if (gb < Btot)
            v = z[(((size_t)n * Btot + gb) * 8 + t) * 32 + c];
        } else if (c < 40) {
          if (idx > 0 && t < idx)
            v = cond_apply(cond_w1, cond_b1, cond_w2, cond_b2, n, c - 32,
                           s_dec[(n * BS + b) * 8 + t]);
        } else {
          if (n > 0 && idx > 0)
            v = cond_apply(cond_w1, cond_b1, cond_w2, cond_b2, n - 1, c - 40,
                           s_dec[((n - 1) * BS + b) * 8 + t]);
        }
        s_x[(b * 8 + t) * 48 + c] = v;
      }
      __syncthreads();
      // ---- stage 2a: proj -> leaky
#pragma unroll 1
      for (int it = tid; it < L * BS * 24; it += NTHREADS) {
        int t = it / (BS * 24);
        int b = (it / 24) & 7;
        int j = it % 24;
        float acc = proj_b[n * 24 + j] +
                    dot48(proj_w + (size_t)(n * 24 + j) * 48, s_x + (b * 8 + t) * 48);
        s_h[(b * 8 + t) * 24 + j] = leaky(acc);
      }
      __syncthreads();
      // ---- stage 2b: gru_proj
#pragma unroll 1
      for (int it = tid; it < L * BS * 24; it += NTHREADS) {
        int t = it / (BS * 24);
        int b = (it / 24) & 7;
        int j = it % 24;
        s_g[(b * 8 + t) * 24 + j] =
            gpb[j] + dot24(gpw + j * 24, s_h + (b * 8 + t) * 24);
      }
      __syncthreads();
      // ---- GRU, 2 layers
#pragma unroll 1
      for (int l = 0; l < 2; ++l) {
        const float* src = (l == 0) ? s_g : s_y;
        const float* wih = gru_wih + (size_t)((n * 2 + l) * 72) * 24;
        const float* bih = gru_bih + (n * 2 + l) * 72;
        const float* whh = gru_whh + (size_t)((n * 2 + l) * 72) * 24;
        const float* bhh = gru_bhh + (n * 2 + l) * 72;
        // input gates for all t (t-parallel)
#pragma unroll 1
        for (int it = tid; it < L * BS * 72; it += NTHREADS) {
          int t = it / (BS * 72);
          int b = (it / 72) & 7;
          int j = it % 72;
          s_gi[(b * 8 + t) * 72 + j] =
              bih[j] + dot24(wih + (size_t)j * 24, src + (b * 8 + t) * 24);
        }
        if (tid < BS * 24) s_hid[tid] = 0.0f;  // buffer 0 = h0
        __syncthreads();
        int cur = 0;
#pragma unroll 1
        for (int t = 0; t < L; ++t) {
          if (tid < BS * 24) {
            int b = tid / 24, j = tid - b * 24;
            const float* h = s_hid + cur * 192 + b * 24;
            float ghr = bhh[j]      + dot24(whh + (size_t)(j)      * 24, h);
            float ghz = bhh[24 + j] + dot24(whh + (size_t)(24 + j) * 24, h);
            float ghn = bhh[48 + j] + dot24(whh + (size_t)(48 + j) * 24, h);
            const float* gi = s_gi + (b * 8 + t) * 72;
            float r  = sigm(gi[j] + ghr);
            float zg = sigm(gi[24 + j] + ghz);
            float nn = tanh_fast(gi[48 + j] + r * ghn);
            float hold = h[j];
            float hnew = fmaf(zg, hold - nn, nn);  // (1-z)*n + z*h
            s_hid[(cur ^ 1) * 192 + b * 24 + j] = hnew;
            s_y[(b * 8 + t) * 24 + j] = hnew;
          }
          cur ^= 1;
          __syncthreads();
        }
      }
      // ---- causal map layer 1 (writes over s_gi region; gi dead)
#pragma unroll 1
      for (int it = tid; it < L * BS * 64; it += NTHREADS) {
        int t = it / (BS * 64);
        int b = (it / 64) & 7;
        int j = it % 64;
        float acc = cm_b1[n * 64 + j] +
                    dot24(cm_w1 + (size_t)(n * 64 + j) * 24, s_y + (b * 8 + t) * 24);
        s_d1[(b * 8 + t) * 64 + j] = fmaxf(acc, 0.0f);
      }
      __syncthreads();
      // ---- causal map layer 2 (writes over s_x region; x dead)
#pragma unroll 1
      for (int it = tid; it < L * BS * 64; it += NTHREADS) {
        int t = it / (BS * 64);
        int b = (it / 64) & 7;
        int j = it % 64;
        float acc = cm_b2[n * 64 + j] +
                    dot64(cm_w2 + (size_t)(n * 64 + j) * 64, s_d1 + (b * 8 + t) * 64);
        s_d2[(b * 8 + t) * 64 + j] = fmaxf(acc, 0.0f);
      }
      __syncthreads();
      // ---- causal map layer 3 -> decoded, and emit out[:, idx, n]
#pragma unroll 1
      for (int it = tid; it < L * BS; it += NTHREADS) {
        int t = it / BS;
        int b = it % BS;
        float dv = cm_b3[n] + dot64(cm_w3 + n * 64, s_d2 + (b * 8 + t) * 64);
        s_dec[(n * BS + b) * 8 + t] = dv;
        int gb = gb0 + b;
        if (t == idx && gb < Btot)
          out[((size_t)gb * T + idx) * 8 + n] = dv;
      }
      __syncthreads();
    }
  }
}

extern "C" void kernel_launch(void* const* d_in, const int* in_sizes, int n_in,
                              void* d_out, int out_size, void* d_ws, size_t ws_size,
                              hipStream_t stream) {
  const float* z       = (const float*)d_in[0];
  const float* cond_w1 = (const float*)d_in[1];
  const float* cond_b1 = (const float*)d_in[2];
  const float* cond_w2 = (const float*)d_in[3];
  const float* cond_b2 = (const float*)d_in[4];
  const float* proj_w  = (const float*)d_in[5];
  const float* proj_b  = (const float*)d_in[6];
  const float* gpw     = (const float*)d_in[7];
  const float* gpb     = (const float*)d_in[8];
  const float* gru_wih = (const float*)d_in[9];
  const float* gru_whh = (const float*)d_in[10];
  const float* gru_bih = (const float*)d_in[11];
  const float* gru_bhh = (const float*)d_in[12];
  const float* cm_w1   = (const float*)d_in[13];
  const float* cm_b1   = (const float*)d_in[14];
  const float* cm_w2   = (const float*)d_in[15];
  const float* cm_b2   = (const float*)d_in[16];
  const float* cm_w3   = (const float*)d_in[17];
  const float* cm_b3   = (const float*)d_in[18];
  const int*   endw    = (const int*)d_in[19];
  float* out = (float*)d_out;

  int Btot = in_sizes[0] / (8 * 8 * 32);  // z: [8, B, 8, 32]
  int nblocks = (Btot + BS - 1) / BS;

  tcm_kernel<<<nblocks, NTHREADS, 0, stream>>>(
      z, cond_w1, cond_b1, cond_w2, cond_b2, proj_w, proj_b, gpw, gpb,
      gru_wih, gru_whh, gru_bih, gru_bhh, cm_w1, cm_b1, cm_w2, cm_b2,
      cm_w3, cm_b3, endw, out, Btot);
}

// Round 2
// 1318.809 us; speedup vs baseline: 1.5176x; 1.5176x over previous
//
#include <hip/hip_runtime.h>

// TemporalCausalMaps on MI355X (gfx950), round 2.
// One sample per block, 64 threads = ONE wave => __syncthreads() lowers to
// waitcnt only (no s_barrier), all activation LDS reads are broadcasts (no
// bank conflicts), 2048 blocks => 8 blocks/CU for latency hiding.

#define NT 64

__device__ __forceinline__ float sigm(float x) { return 1.0f / (1.0f + __expf(-x)); }
__device__ __forceinline__ float tanh_fast(float x) {
  x = fminf(15.0f, fmaxf(-15.0f, x));
  float e = __expf(2.0f * x);
  return (e - 1.0f) / (e + 1.0f);
}
__device__ __forceinline__ float leaky(float x) { return x >= 0.0f ? x : 0.01f * x; }

template <int N4>
__device__ __forceinline__ float dotv(const float* __restrict__ w, const float* h) {
  const float4* w4 = reinterpret_cast<const float4*>(w);
  const float4* h4 = reinterpret_cast<const float4*>(h);
  float acc = 0.0f;
#pragma unroll
  for (int i = 0; i < N4; ++i) {
    float4 a = w4[i], b = h4[i];
    acc = fmaf(a.x, b.x, acc); acc = fmaf(a.y, b.y, acc);
    acc = fmaf(a.z, b.z, acc); acc = fmaf(a.w, b.w, acc);
  }
  return acc;
}

// cond_net: out_e = b2[e] + sum_k w2[e,k] * relu(xv * w1[k] + b1[k])
__device__ __forceinline__ float cond_apply(
    const float* __restrict__ cw1, const float* __restrict__ cb1,
    const float* __restrict__ cw2, const float* __restrict__ cb2,
    int nn, int e, float xv) {
  const float4* w1 = reinterpret_cast<const float4*>(cw1 + nn * 32);
  const float4* b1 = reinterpret_cast<const float4*>(cb1 + nn * 32);
  const float4* w2 = reinterpret_cast<const float4*>(cw2 + (nn * 8 + e) * 32);
  float acc = cb2[nn * 8 + e];
#pragma unroll
  for (int i = 0; i < 8; ++i) {
    float4 a = w1[i], c = b1[i], d = w2[i];
    float h0 = fmaxf(fmaf(xv, a.x, c.x), 0.0f);
    float h1 = fmaxf(fmaf(xv, a.y, c.y), 0.0f);
    float h2 = fmaxf(fmaf(xv, a.z, c.z), 0.0f);
    float h3 = fmaxf(fmaf(xv, a.w, c.w), 0.0f);
    acc = fmaf(d.x, h0, acc); acc = fmaf(d.y, h1, acc);
    acc = fmaf(d.z, h2, acc); acc = fmaf(d.w, h3, acc);
  }
  return acc;
}

// LDS layout (floats), all offsets 16B-aligned. Total 2672 floats = 10688 B.
//  s_x   [8][48]  @0      stage-1 input
//  s_h   [8][24]  @384    proj out
//  s_g   [8][24]  @576    gru input
//  s_gi  [8][72]  @768    input gates
//  s_y   [8][24]  @1344   GRU layer out
//  s_hid [2][24]  @1536   double-buffered hidden
//  s_d1  [8][64]  @1584   causal-map hidden 1
//  s_d2  [8][64]  @2096   causal-map hidden 2
//  s_dec [8][8]   @2608   decoded [node][t]
__global__ __launch_bounds__(NT, 2) void tcm_kernel(
    const float* __restrict__ z,
    const float* __restrict__ cond_w1, const float* __restrict__ cond_b1,
    const float* __restrict__ cond_w2, const float* __restrict__ cond_b2,
    const float* __restrict__ proj_w, const float* __restrict__ proj_b,
    const float* __restrict__ gpw, const float* __restrict__ gpb,
    const float* __restrict__ gru_wih, const float* __restrict__ gru_whh,
    const float* __restrict__ gru_bih, const float* __restrict__ gru_bhh,
    const float* __restrict__ cm_w1, const float* __restrict__ cm_b1,
    const float* __restrict__ cm_w2, const float* __restrict__ cm_b2,
    const float* __restrict__ cm_w3, const float* __restrict__ cm_b3,
    const int* __restrict__ endw,
    float* __restrict__ out, int Btot) {
  __shared__ __align__(16) float lds[2672];
  float* s_x   = lds;
  float* s_h   = lds + 384;
  float* s_g   = lds + 576;
  float* s_gi  = lds + 768;
  float* s_y   = lds + 1344;
  float* s_hid = lds + 1536;
  float* s_d1  = lds + 1584;
  float* s_d2  = lds + 2096;
  float* s_dec = lds + 2608;

  const int lane = threadIdx.x;
  const int b = blockIdx.x;
  const int T = endw[0];

#pragma unroll 1
  for (int idx = 0; idx < T; ++idx) {
    const int L = idx + 1;
#pragma unroll 1
    for (int n = 0; n < 8; ++n) {
      // ---- stage 1a: copy z prefix (float4) into s_x[t][0:32]
      {
        const float4* z4 = reinterpret_cast<const float4*>(
            z + ((size_t)n * Btot + b) * 8 * 32);
        float4* x4 = reinterpret_cast<float4*>(s_x);
#pragma unroll 1
        for (int it = lane; it < L * 8; it += NT) {
          int t = it >> 3, q = it & 7;
          x4[t * 12 + q] = z4[t * 8 + q];
        }
      }
      // ---- stage 1b: cond embeddings into s_x[t][32:48]
#pragma unroll 1
      for (int it = lane; it < L * 16; it += NT) {
        int t = it >> 4, c = it & 15;
        float v = 0.0f;
        if (c < 8) {
          if (idx > 0 && t < idx)
            v = cond_apply(cond_w1, cond_b1, cond_w2, cond_b2, n, c,
                           s_dec[n * 8 + t]);
        } else {
          if (n > 0 && idx > 0)
            v = cond_apply(cond_w1, cond_b1, cond_w2, cond_b2, n - 1, c - 8,
                           s_dec[(n - 1) * 8 + t]);
        }
        s_x[t * 48 + 32 + c] = v;
      }
      __syncthreads();
      // ---- proj -> leaky
#pragma unroll 1
      for (int it = lane; it < L * 24; it += NT) {
        int t = it / 24, j = it % 24;
        float acc = proj_b[n * 24 + j] +
                    dotv<12>(proj_w + (size_t)(n * 24 + j) * 48, s_x + t * 48);
        s_h[t * 24 + j] = leaky(acc);
      }
      __syncthreads();
      // ---- gru_proj
#pragma unroll 1
      for (int it = lane; it < L * 24; it += NT) {
        int t = it / 24, j = it % 24;
        s_g[t * 24 + j] = gpb[j] + dotv<6>(gpw + j * 24, s_h + t * 24);
      }
      __syncthreads();
      // ---- GRU, 2 layers
      const float* src = s_g;
#pragma unroll 1
      for (int l = 0; l < 2; ++l) {
        const int nl = n * 2 + l;
        const float* wih = gru_wih + (size_t)nl * 72 * 24;
        const float* bih = gru_bih + nl * 72;
        const float* whh = gru_whh + (size_t)nl * 72 * 24;
        const float* bhh = gru_bhh + nl * 72;
        // input gates, t-parallel
#pragma unroll 1
        for (int it = lane; it < L * 72; it += NT) {
          int t = it / 72, j = it % 72;
          s_gi[t * 72 + j] = bih[j] + dotv<6>(wih + (size_t)j * 24, src + t * 24);
        }
        // hoist whh rows (j, 24+j, 48+j) into registers
        int jm = lane < 24 ? lane : (lane < 48 ? lane - 24 : lane - 48);
        float4 Wr[6], Wz[6], Wn[6];
        {
          const float4* wr4 = reinterpret_cast<const float4*>(whh + jm * 24);
          const float4* wz4 = reinterpret_cast<const float4*>(whh + (24 + jm) * 24);
          const float4* wn4 = reinterpret_cast<const float4*>(whh + (48 + jm) * 24);
#pragma unroll
          for (int i = 0; i < 6; ++i) { Wr[i] = wr4[i]; Wz[i] = wz4[i]; Wn[i] = wn4[i]; }
        }
        float bR = bhh[jm], bZ = bhh[24 + jm], bN = bhh[48 + jm];
        if (lane < 24) s_hid[lane] = 0.0f;
        __syncthreads();
        int cur = 0;
#pragma unroll 1
        for (int t = 0; t < L; ++t) {
          if (lane < 24) {
            const float4* hp = reinterpret_cast<const float4*>(s_hid + cur * 24);
            float gr = bR, gz = bZ, gn = bN;
#pragma unroll
            for (int i = 0; i < 6; ++i) {
              float4 hh = hp[i];
              gr = fmaf(Wr[i].x, hh.x, gr); gr = fmaf(Wr[i].y, hh.y, gr);
              gr = fmaf(Wr[i].z, hh.z, gr); gr = fmaf(Wr[i].w, hh.w, gr);
              gz = fmaf(Wz[i].x, hh.x, gz); gz = fmaf(Wz[i].y, hh.y, gz);
              gz = fmaf(Wz[i].z, hh.z, gz); gz = fmaf(Wz[i].w, hh.w, gz);
              gn = fmaf(Wn[i].x, hh.x, gn); gn = fmaf(Wn[i].y, hh.y, gn);
              gn = fmaf(Wn[i].z, hh.z, gn); gn = fmaf(Wn[i].w, hh.w, gn);
            }
            const float* gi = s_gi + t * 72;
            float r  = sigm(gi[lane] + gr);
            float zg = sigm(gi[24 + lane] + gz);
            float nn2 = tanh_fast(gi[48 + lane] + r * gn);
            float hold = s_hid[cur * 24 + lane];
            float hnew = fmaf(zg, hold - nn2, nn2);  // (1-z)*n + z*h
            s_hid[(cur ^ 1) * 24 + lane] = hnew;
            s_y[t * 24 + lane] = hnew;
          }
          cur ^= 1;
          __syncthreads();
        }
        src = s_y;
      }
      // ---- causal map layer 1
#pragma unroll 1
      for (int it = lane; it < L * 64; it += NT) {
        int t = it >> 6, j = it & 63;
        float acc = cm_b1[n * 64 + j] +
                    dotv<6>(cm_w1 + (size_t)(n * 64 + j) * 24, s_y + t * 24);
        s_d1[t * 64 + j] = fmaxf(acc, 0.0f);
      }
      __syncthreads();
      // ---- causal map layer 2
#pragma unroll 1
      for (int it = lane; it < L * 64; it += NT) {
        int t = it >> 6, j = it & 63;
        float acc = cm_b2[n * 64 + j] +
                    dotv<16>(cm_w2 + (size_t)(n * 64 + j) * 64, s_d1 + t * 64);
        s_d2[t * 64 + j] = fmaxf(acc, 0.0f);
      }
      __syncthreads();
      // ---- causal map layer 3 -> decoded + emit
      if (lane < L) {
        int t = lane;
        float dv = cm_b3[n] + dotv<16>(cm_w3 + n * 64, s_d2 + t * 64);
        s_dec[n * 8 + t] = dv;
        if (t == idx)
          out[((size_t)b * T + idx) * 8 + n] = dv;
      }
      __syncthreads();
    }
  }
}

extern "C" void kernel_launch(void* const* d_in, const int* in_sizes, int n_in,
                              void* d_out, int out_size, void* d_ws, size_t ws_size,
                              hipStream_t stream) {
  const float* z       = (const float*)d_in[0];
  const float* cond_w1 = (const float*)d_in[1];
  const float* cond_b1 = (const float*)d_in[2];
  const float* cond_w2 = (const float*)d_in[3];
  const float* cond_b2 = (const float*)d_in[4];
  const float* proj_w  = (const float*)d_in[5];
  const float* proj_b  = (const float*)d_in[6];
  const float* gpw     = (const float*)d_in[7];
  const float* gpb     = (const float*)d_in[8];
  const float* gru_wih = (const float*)d_in[9];
  const float* gru_whh = (const float*)d_in[10];
  const float* gru_bih = (const float*)d_in[11];
  const float* gru_bhh = (const float*)d_in[12];
  const float* cm_w1   = (const float*)d_in[13];
  const float* cm_b1   = (const float*)d_in[14];
  const float* cm_w2   = (const float*)d_in[15];
  const float* cm_b2   = (const float*)d_in[16];
  const float* cm_w3   = (const float*)d_in[17];
  const float* cm_b3   = (const float*)d_in[18];
  const int*   endw    = (const int*)d_in[19];
  float* out = (float*)d_out;

  int Btot = in_sizes[0] / (8 * 8 * 32);  // z: [8, B, 8, 32]

  tcm_kernel<<<Btot, NT, 0, stream>>>(
      z, cond_w1, cond_b1, cond_w2, cond_b2, proj_w, proj_b, gpw, gpb,
      gru_wih, gru_whh, gru_bih, gru_bhh, cm_w1, cm_b1, cm_w2, cm_b2,
      cm_w3, cm_b3, endw, out, Btot);
}

// Round 3
// 1197.651 us; speedup vs baseline: 1.6711x; 1.1012x over previous
//
#include <hip/hip_runtime.h>

// TemporalCausalMaps on MI355X (gfx950), round 3.
// One sample per block, one wave per block (no s_barrier, LDS broadcasts).
// Wide stages (64/72 outputs) use lane=output-neuron with weight rows hoisted
// into VGPRs once per (idx,node) cell; activations read as LDS broadcasts.

#define NT 64

__device__ __forceinline__ float sigm(float x) { return 1.0f / (1.0f + __expf(-x)); }
__device__ __forceinline__ float tanh_fast(float x) {
  x = fminf(15.0f, fmaxf(-15.0f, x));
  float e = __expf(2.0f * x);
  return (e - 1.0f) / (e + 1.0f);
}
__device__ __forceinline__ float leaky(float x) { return x >= 0.0f ? x : 0.01f * x; }

template <int N4>
__device__ __forceinline__ float dotv(const float* __restrict__ w, const float* h) {
  const float4* w4 = reinterpret_cast<const float4*>(w);
  const float4* h4 = reinterpret_cast<const float4*>(h);
  float acc = 0.0f;
#pragma unroll
  for (int i = 0; i < N4; ++i) {
    float4 a = w4[i], b = h4[i];
    acc = fmaf(a.x, b.x, acc); acc = fmaf(a.y, b.y, acc);
    acc = fmaf(a.z, b.z, acc); acc = fmaf(a.w, b.w, acc);
  }
  return acc;
}

// LDS layout (floats), 16B-aligned offsets. Total 3248 floats = 12992 B.
//  s_x   [8][48]  @0       s_h  [8][24] @384    s_g   [8][24] @576
//  s_gi  [8][72]  @768     s_y  [8][24] @1344   s_hid [2][24] @1536
//  s_d1  [8][68]  @1584    s_d2 [8][68] @2128   s_dec [8][8]  @2672
//  s_ch  [8][2][32] @2736  (cond-net relu hidden, [t][src][k])
__global__ __launch_bounds__(NT, 2) void tcm_kernel(
    const float* __restrict__ z,
    const float* __restrict__ cond_w1, const float* __restrict__ cond_b1,
    const float* __restrict__ cond_w2, const float* __restrict__ cond_b2,
    const float* __restrict__ proj_w, const float* __restrict__ proj_b,
    const float* __restrict__ gpw, const float* __restrict__ gpb,
    const float* __restrict__ gru_wih, const float* __restrict__ gru_whh,
    const float* __restrict__ gru_bih, const float* __restrict__ gru_bhh,
    const float* __restrict__ cm_w1, const float* __restrict__ cm_b1,
    const float* __restrict__ cm_w2, const float* __restrict__ cm_b2,
    const float* __restrict__ cm_w3, const float* __restrict__ cm_b3,
    const int* __restrict__ endw,
    float* __restrict__ out, int Btot) {
  __shared__ __align__(16) float lds[3248];
  float* s_x   = lds;
  float* s_h   = lds + 384;
  float* s_g   = lds + 576;
  float* s_gi  = lds + 768;
  float* s_y   = lds + 1344;
  float* s_hid = lds + 1536;
  float* s_d1  = lds + 1584;   // stride 68
  float* s_d2  = lds + 2128;   // stride 68
  float* s_dec = lds + 2672;
  float* s_ch  = lds + 2736;

  const int lane = threadIdx.x;
  const int b = blockIdx.x;
  const int T = endw[0];

  s_dec[lane] = 0.0f;  // avoid Inf/NaN garbage in gated paths
  __syncthreads();

#pragma unroll 1
  for (int idx = 0; idx < T; ++idx) {
    const int L = idx + 1;
#pragma unroll 1
    for (int n = 0; n < 8; ++n) {
      // ---- stage 1a: copy z prefix (float4) into s_x[t][0:32]
      {
        const float4* z4 = reinterpret_cast<const float4*>(
            z + ((size_t)n * Btot + b) * 8 * 32);
        float4* x4 = reinterpret_cast<float4*>(s_x);
#pragma unroll 1
        for (int it = lane; it < L * 8; it += NT) {
          int t = it >> 3, q = it & 7;
          x4[t * 12 + q] = z4[t * 8 + q];
        }
      }
      // ---- stage 1b phase 1: cond relu hidden, lane = (src, k)
      if (idx > 0) {
        int src = lane >> 5, k = lane & 31;
        int nn = (src == 0) ? n : (n > 0 ? n - 1 : 0);
        float w1v = cond_w1[nn * 32 + k];
        float b1v = cond_b1[nn * 32 + k];
#pragma unroll 1
        for (int t = 0; t < L; ++t) {
          float xv = s_dec[nn * 8 + t];
          s_ch[t * 64 + lane] = fmaxf(fmaf(xv, w1v, b1v), 0.0f);
        }
      }
      __syncthreads();
      // ---- stage 1b phase 2: cond output dot32 -> s_x[t][32:48]
#pragma unroll 1
      for (int it = lane; it < L * 16; it += NT) {
        int t = it >> 4, c = it & 15;
        float v = 0.0f;
        if (c < 8) {
          if (t < idx)
            v = cond_b2[n * 8 + c] +
                dotv<8>(cond_w2 + (size_t)(n * 8 + c) * 32, s_ch + t * 64);
        } else {
          if (n > 0 && idx > 0)
            v = cond_b2[(n - 1) * 8 + (c - 8)] +
                dotv<8>(cond_w2 + (size_t)((n - 1) * 8 + c - 8) * 32,
                        s_ch + t * 64 + 32);
        }
        s_x[t * 48 + 32 + c] = v;
      }
      __syncthreads();
      // ---- proj -> leaky (24 outputs, item-mapped)
#pragma unroll 1
      for (int it = lane; it < L * 24; it += NT) {
        int t = it / 24, j = it % 24;
        float acc = proj_b[n * 24 + j] +
                    dotv<12>(proj_w + (size_t)(n * 24 + j) * 48, s_x + t * 48);
        s_h[t * 24 + j] = leaky(acc);
      }
      __syncthreads();
      // ---- gru_proj (24 outputs, item-mapped)
#pragma unroll 1
      for (int it = lane; it < L * 24; it += NT) {
        int t = it / 24, j = it % 24;
        s_g[t * 24 + j] = gpb[j] + dotv<6>(gpw + j * 24, s_h + t * 24);
      }
      __syncthreads();
      // ---- GRU, 2 layers
      const float* src = s_g;
#pragma unroll 1
      for (int l = 0; l < 2; ++l) {
        const int nl = n * 2 + l;
        const float* wih = gru_wih + (size_t)nl * 72 * 24;
        const float* bih = gru_bih + nl * 72;
        const float* whh = gru_whh + (size_t)nl * 72 * 24;
        const float* bhh = gru_bhh + nl * 72;
        // input gates: lane = row (rows 0..63), rows 64..71 on lanes 0..7;
        // weight rows hoisted to VGPRs, activation read as LDS broadcast.
        {
          float4 WA[6], WB[6];
          const float4* wa = reinterpret_cast<const float4*>(wih + (size_t)lane * 24);
          const float4* wb = reinterpret_cast<const float4*>(
              wih + (size_t)(64 + (lane & 7)) * 24);
#pragma unroll
          for (int i = 0; i < 6; ++i) { WA[i] = wa[i]; WB[i] = wb[i]; }
          float bA = bih[lane];
          float bB = bih[64 + (lane & 7)];
#pragma unroll 1
          for (int t = 0; t < L; ++t) {
            const float4* h4 = reinterpret_cast<const float4*>(src + t * 24);
            float accA = bA, accB = bB;
#pragma unroll
            for (int i = 0; i < 6; ++i) {
              float4 hh = h4[i];
              accA = fmaf(WA[i].x, hh.x, accA); accA = fmaf(WA[i].y, hh.y, accA);
              accA = fmaf(WA[i].z, hh.z, accA); accA = fmaf(WA[i].w, hh.w, accA);
              accB = fmaf(WB[i].x, hh.x, accB); accB = fmaf(WB[i].y, hh.y, accB);
              accB = fmaf(WB[i].z, hh.z, accB); accB = fmaf(WB[i].w, hh.w, accB);
            }
            s_gi[t * 72 + lane] = accA;
            if (lane < 8) s_gi[t * 72 + 64 + lane] = accB;
          }
        }
        // hoist whh rows (j, 24+j, 48+j) into registers
        int jm = lane < 24 ? lane : (lane < 48 ? lane - 24 : lane - 48);
        float4 Wr[6], Wz[6], Wn[6];
        {
          const float4* wr4 = reinterpret_cast<const float4*>(whh + jm * 24);
          const float4* wz4 = reinterpret_cast<const float4*>(whh + (24 + jm) * 24);
          const float4* wn4 = reinterpret_cast<const float4*>(whh + (48 + jm) * 24);
#pragma unroll
          for (int i = 0; i < 6; ++i) { Wr[i] = wr4[i]; Wz[i] = wz4[i]; Wn[i] = wn4[i]; }
        }
        float bR = bhh[jm], bZ = bhh[24 + jm], bN = bhh[48 + jm];
        if (lane < 24) s_hid[lane] = 0.0f;
        __syncthreads();
        int cur = 0;
#pragma unroll 1
        for (int t = 0; t < L; ++t) {
          if (lane < 24) {
            const float4* hp = reinterpret_cast<const float4*>(s_hid + cur * 24);
            float gr = bR, gz = bZ, gn = bN;
#pragma unroll
            for (int i = 0; i < 6; ++i) {
              float4 hh = hp[i];
              gr = fmaf(Wr[i].x, hh.x, gr); gr = fmaf(Wr[i].y, hh.y, gr);
              gr = fmaf(Wr[i].z, hh.z, gr); gr = fmaf(Wr[i].w, hh.w, gr);
              gz = fmaf(Wz[i].x, hh.x, gz); gz = fmaf(Wz[i].y, hh.y, gz);
              gz = fmaf(Wz[i].z, hh.z, gz); gz = fmaf(Wz[i].w, hh.w, gz);
              gn = fmaf(Wn[i].x, hh.x, gn); gn = fmaf(Wn[i].y, hh.y, gn);
              gn = fmaf(Wn[i].z, hh.z, gn); gn = fmaf(Wn[i].w, hh.w, gn);
            }
            const float* gi = s_gi + t * 72;
            float r   = sigm(gi[lane] + gr);
            float zg  = sigm(gi[24 + lane] + gz);
            float nn2 = tanh_fast(gi[48 + lane] + r * gn);
            float hold = s_hid[cur * 24 + lane];
            float hnew = fmaf(zg, hold - nn2, nn2);  // (1-z)*n + z*h
            s_hid[(cur ^ 1) * 24 + lane] = hnew;
            s_y[t * 24 + lane] = hnew;
          }
          cur ^= 1;
          __syncthreads();
        }
        src = s_y;
      }
      // ---- causal map layer 1: lane = j (64 outputs), reg weights
      {
        float4 W[6];
        const float4* w4 = reinterpret_cast<const float4*>(
            cm_w1 + (size_t)(n * 64 + lane) * 24);
#pragma unroll
        for (int i = 0; i < 6; ++i) W[i] = w4[i];
        float bb = cm_b1[n * 64 + lane];
#pragma unroll 1
        for (int t = 0; t < L; ++t) {
          const float4* y4 = reinterpret_cast<const float4*>(s_y + t * 24);
          float acc = bb;
#pragma unroll
          for (int i = 0; i < 6; ++i) {
            float4 hh = y4[i];
            acc = fmaf(W[i].x, hh.x, acc); acc = fmaf(W[i].y, hh.y, acc);
            acc = fmaf(W[i].z, hh.z, acc); acc = fmaf(W[i].w, hh.w, acc);
          }
          s_d1[t * 68 + lane] = fmaxf(acc, 0.0f);
        }
      }
      __syncthreads();
      // ---- causal map layer 2: lane = j (64 outputs), reg weights
      {
        float4 W[16];
        const float4* w4 = reinterpret_cast<const float4*>(
            cm_w2 + (size_t)(n * 64 + lane) * 64);
#pragma unroll
        for (int i = 0; i < 16; ++i) W[i] = w4[i];
        float bb = cm_b2[n * 64 + lane];
#pragma unroll 1
        for (int t = 0; t < L; ++t) {
          const float4* d4 = reinterpret_cast<const float4*>(s_d1 + t * 68);
          float acc = bb;
#pragma unroll
          for (int i = 0; i < 16; ++i) {
            float4 hh = d4[i];
            acc = fmaf(W[i].x, hh.x, acc); acc = fmaf(W[i].y, hh.y, acc);
            acc = fmaf(W[i].z, hh.z, acc); acc = fmaf(W[i].w, hh.w, acc);
          }
          s_d2[t * 68 + lane] = fmaxf(acc, 0.0f);
        }
      }
      __syncthreads();
      // ---- causal map layer 3 -> decoded + emit (w3 row is lane-uniform)
      if (lane < L) {
        int t = lane;
        float dv = cm_b3[n] + dotv<16>(cm_w3 + n * 64, s_d2 + t * 68);
        s_dec[n * 8 + t] = dv;
        if (t == idx)
          out[((size_t)b * T + idx) * 8 + n] = dv;
      }
      __syncthreads();
    }
  }
}

extern "C" void kernel_launch(void* const* d_in, const int* in_sizes, int n_in,
                              void* d_out, int out_size, void* d_ws, size_t ws_size,
                              hipStream_t stream) {
  const float* z       = (const float*)d_in[0];
  const float* cond_w1 = (const float*)d_in[1];
  const float* cond_b1 = (const float*)d_in[2];
  const float* cond_w2 = (const float*)d_in[3];
  const float* cond_b2 = (const float*)d_in[4];
  const float* proj_w  = (const float*)d_in[5];
  const float* proj_b  = (const float*)d_in[6];
  const float* gpw     = (const float*)d_in[7];
  const float* gpb     = (const float*)d_in[8];
  const float* gru_wih = (const float*)d_in[9];
  const float* gru_whh = (const float*)d_in[10];
  const float* gru_bih = (const float*)d_in[11];
  const float* gru_bhh = (const float*)d_in[12];
  const float* cm_w1   = (const float*)d_in[13];
  const float* cm_b1   = (const float*)d_in[14];
  const float* cm_w2   = (const float*)d_in[15];
  const float* cm_b2   = (const float*)d_in[16];
  const float* cm_w3   = (const float*)d_in[17];
  const float* cm_b3   = (const float*)d_in[18];
  const int*   endw    = (const int*)d_in[19];
  float* out = (float*)d_out;

  int Btot = in_sizes[0] / (8 * 8 * 32);  // z: [8, B, 8, 32]

  tcm_kernel<<<Btot, NT, 0, stream>>>(
      z, cond_w1, cond_b1, cond_w2, cond_b2, proj_w, proj_b, gpw, gpb,
      gru_wih, gru_whh, gru_bih, gru_bhh, cm_w1, cm_b1, cm_w2, cm_b2,
      cm_w3, cm_b3, endw, out, Btot);
}